// Round 9
// baseline (239.772 us; speedup 1.0000x reference)
//
#include <hip/hip_runtime.h>
#include <hip/hip_bf16.h>

#define BB   8
#define CIN  64
#define COUT 64
#define HH   128
#define WW   128
#define HWSZ (HH * WW)

typedef short bf16x8 __attribute__((ext_vector_type(8)));
typedef float f32x4  __attribute__((ext_vector_type(4)));
typedef float f32x2  __attribute__((ext_vector_type(2)));

__device__ __forceinline__ unsigned f2bf_u(float f) {
    unsigned u = __float_as_uint(f);
    return (u + 0x7fffu + ((u >> 16) & 1u)) >> 16;
}

// packed bilinear combine of one 2-channel pair across 4 corners (v_pk_fma_f32)
__device__ __forceinline__ unsigned comb2(unsigned a, unsigned b, unsigned c, unsigned d,
                                          f32x2 W0, f32x2 W1, f32x2 W2, f32x2 W3) {
    f32x2 A = {__uint_as_float(a << 16), __uint_as_float(a & 0xffff0000u)};
    f32x2 B = {__uint_as_float(b << 16), __uint_as_float(b & 0xffff0000u)};
    f32x2 C = {__uint_as_float(c << 16), __uint_as_float(c & 0xffff0000u)};
    f32x2 D = {__uint_as_float(d << 16), __uint_as_float(d & 0xffff0000u)};
    f32x2 r = A * W0;
    r += B * W1;
    r += C * W2;
    r += D * W3;
    __hip_bfloat162 h = __float22bfloat162_rn(make_float2(r.x, r.y));
    return *(const unsigned*)&h;
}

// ---------------------------------------------------------------------------
// k_tr: x NCHW fp32 -> xT NHWC bf16, XCD-swizzled (b = id & 7).
//       Blocks 512..575: weight repack; block 512 also zeroes sums.
// ---------------------------------------------------------------------------
__global__ __launch_bounds__(256) void k_tr(const float* __restrict__ x,
                                            const float* __restrict__ wd,
                                            const float* __restrict__ wof,
                                            unsigned short* __restrict__ xT,
                                            unsigned short* __restrict__ wdT,
                                            unsigned short* __restrict__ wofT,
                                            float4* __restrict__ sums4)
{
    const int t = threadIdx.x;
    const int id = blockIdx.x;
    if (id >= 512) {
        if (id == 512) sums4[t] = make_float4(0.f, 0.f, 0.f, 0.f);  // 4096 B
        int base = (id - 512) * 256 + t;
#pragma unroll
        for (int j = 0; j < 4; ++j) {
            int idx = base + j * 16384;
            if (idx < 36864) {
                int k = idx >> 12, rem = idx & 4095, co = rem >> 6, c = rem & 63;
                wdT[idx] = (unsigned short)f2bf_u(wd[(co * 64 + c) * 9 + k]);
            } else if (idx < 55296) {
                int jj = idx - 36864;
                int k = jj >> 11, rem = jj & 2047, o = rem >> 6, c = rem & 63;
                wofT[jj] = (o < 27) ? (unsigned short)f2bf_u(wof[(o * 64 + c) * 9 + k]) : 0;
            }
        }
        return;
    }
    __shared__ unsigned short tile[256 * 66];
    const int b = id & 7;                 // XCD = linear_id % 8 = b
    const int p0 = (id >> 3) * 256;
#pragma unroll
    for (int i = 0; i < 16; ++i) {
        int c = i * 4 + (t >> 6);
        int pl = (t & 63) * 4;
        float4 v = *(const float4*)(x + (((size_t)b * 64 + c) << 14) + p0 + pl);
        tile[(pl + 0) * 66 + c] = (unsigned short)f2bf_u(v.x);
        tile[(pl + 1) * 66 + c] = (unsigned short)f2bf_u(v.y);
        tile[(pl + 2) * 66 + c] = (unsigned short)f2bf_u(v.z);
        tile[(pl + 3) * 66 + c] = (unsigned short)f2bf_u(v.w);
    }
    __syncthreads();
#pragma unroll
    for (int i = 0; i < 8; ++i) {
        int idd = i * 256 + t;
        int pt = idd >> 3, ck = idd & 7;
        const unsigned* srcp = (const unsigned*)&tile[pt * 66 + ck * 8];
        uint4 r;
        r.x = srcp[0]; r.y = srcp[1]; r.z = srcp[2]; r.w = srcp[3];
        *(uint4*)(xT + ((size_t)b << 20) + (size_t)(p0 + pt) * 64 + ck * 8) = r;
    }
}

// ---------------------------------------------------------------------------
// k_off: offset conv, XCD-swizzled. 4-row x 130-col zero-padded halo tile;
//        inner loop = pure ds_read + MFMA.
// ---------------------------------------------------------------------------
__global__ __launch_bounds__(256, 2) void k_off(
    const unsigned short* __restrict__ xT, const unsigned short* __restrict__ wofT,
    const float* __restrict__ bof, float* __restrict__ om)
{
    __shared__ unsigned short tile[8 * 521 * 8];   // 66,688 B
    const int t = threadIdx.x;
    const int lane = t & 63, wv = t >> 6;
    const int q = lane >> 4, l15 = lane & 15;
    const int b = blockIdx.x & 7;                  // XCD = b
    const int xblk = blockIdx.x >> 3;
    const int h0 = xblk * 2;
    const int r0 = h0 - 1;
    const unsigned short* xb = xT + ((size_t)b << 20);

#pragma unroll
    for (int i = 0; i < 17; ++i) {
        int id = i * 256 + t;
        if (id < 4160) {
            int m = id & 7, lin = id >> 3;
            int row = lin / 130, col = lin % 130;
            int gy = r0 + row, gx = col - 1;
            uint4 v = {0u, 0u, 0u, 0u};
            if (((unsigned)gy < (unsigned)HH) && ((unsigned)gx < (unsigned)WW))
                v = *(const uint4*)(xb + ((size_t)(gy * WW + gx) << 6) + m * 8);
            *(uint4*)&tile[(m * 521 + lin) * 8] = v;
        }
    }
    __syncthreads();

    const int hrow = h0 + (wv >> 1);
    const int c0 = (wv & 1) * 64;

    f32x4 acc[2][4];
#pragma unroll
    for (int mt = 0; mt < 2; ++mt)
#pragma unroll
        for (int nt = 0; nt < 4; ++nt) acc[mt][nt] = (f32x4){0.f, 0.f, 0.f, 0.f};

#pragma unroll
    for (int k = 0; k < 9; ++k) {
        const int ky = k / 3 - 1, kx = k % 3 - 1;
        const int trow = (hrow - h0) + ky + 1;
        const unsigned short* wk = wofT + k * 2048;
#pragma unroll
        for (int ks = 0; ks < 2; ++ks) {
            bf16x8 af[2], bfr[4];
#pragma unroll
            for (int mt = 0; mt < 2; ++mt)
                af[mt] = *(const bf16x8*)(wk + (mt * 16 + l15) * 64 + ks * 32 + q * 8);
#pragma unroll
            for (int nt = 0; nt < 4; ++nt) {
                int tc = c0 + nt * 16 + l15 + kx + 1;
                bfr[nt] = *(const bf16x8*)&tile[((ks * 4 + q) * 521 + trow * 130 + tc) * 8];
            }
#pragma unroll
            for (int mt = 0; mt < 2; ++mt)
#pragma unroll
                for (int nt = 0; nt < 4; ++nt)
                    acc[mt][nt] = __builtin_amdgcn_mfma_f32_16x16x32_bf16(
                        af[mt], bfr[nt], acc[mt][nt], 0, 0, 0);
        }
    }

    const int p0 = xblk * 256 + wv * 64;
    float* omb = om + (size_t)b * 27 * HWSZ;
#pragma unroll
    for (int mt = 0; mt < 2; ++mt)
#pragma unroll
        for (int r = 0; r < 4; ++r) {
            int o = mt * 16 + q * 4 + r;
            if (o < 27) {
                float bias = bof[o];
#pragma unroll
                for (int nt = 0; nt < 4; ++nt) {
                    int pp = p0 + nt * 16 + l15;
                    float v = acc[mt][nt][r] + bias;
                    if (o >= 18) v = 1.f / (1.f + __expf(-v));
                    omb[(size_t)o * HWSZ + pp] = v;
                }
            }
        }
}

// ---------------------------------------------------------------------------
// k_dcn: XCD-swizzled, 64 pts/wave, 4 blocks/CU. Addresses/weights broadcast
//        via __shfl (no LDS publish); coalesced cooperative gather with
//        distance-2 pipeline; packed combine; MFMA; fused stats.
// ---------------------------------------------------------------------------
__global__ __launch_bounds__(256, 4) void k_dcn(
    const unsigned short* __restrict__ xT, const float* __restrict__ om,
    const unsigned short* __restrict__ wdT, const float* __restrict__ bd,
    float* __restrict__ out, float2* __restrict__ sums)
{
    __shared__ unsigned short col_sh[4][64 * 72];   // 36864 B
    __shared__ float          redS[4][64];          //  1024 B
    __shared__ float          redQ[4][64];          //  1024 B

    const int t = threadIdx.x;
    const int lane = t & 63, wv = t >> 6;
    const int q = lane >> 4, l15 = lane & 15;
    const int b = blockIdx.x & 7;                   // XCD = b
    const int pblk = (blockIdx.x >> 3) * 256;
    const int p = pblk + t;
    const int h = p >> 7, w = p & 127;
    const char* xbB = (const char*)(xT + ((size_t)b << 20));
    const float* omp = om + (size_t)b * 27 * HWSZ + p;
    const int gck = lane & 7;

    f32x4 acc[4][4];
#pragma unroll
    for (int mt = 0; mt < 4; ++mt)
#pragma unroll
        for (int nt = 0; nt < 4; ++nt) acc[mt][nt] = (f32x4){0.f, 0.f, 0.f, 0.f};

    // per-lane corner addresses (a0..a3) and bilinear weights (wb0..wb3),
    // broadcast to the cooperative gather via __shfl.
#define LOADG(P, g) { \
    int pt_ = (g) * 8 + (lane >> 3); \
    unsigned o0_ = (unsigned)__shfl((int)a0, pt_); \
    unsigned o1_ = (unsigned)__shfl((int)a1, pt_); \
    unsigned o2_ = (unsigned)__shfl((int)a2, pt_); \
    unsigned o3_ = (unsigned)__shfl((int)a3, pt_); \
    int bo_ = gck * 16; \
    P[0] = *(const uint4*)(xbB + o0_ + bo_); \
    P[1] = *(const uint4*)(xbB + o1_ + bo_); \
    P[2] = *(const uint4*)(xbB + o2_ + bo_); \
    P[3] = *(const uint4*)(xbB + o3_ + bo_); }

#define COMBG(P, g) { \
    int pt_ = (g) * 8 + (lane >> 3); \
    float w0_ = __shfl(wb0, pt_), w1_ = __shfl(wb1, pt_); \
    float w2_ = __shfl(wb2, pt_), w3_ = __shfl(wb3, pt_); \
    f32x2 W0_ = {w0_, w0_}, W1_ = {w1_, w1_}; \
    f32x2 W2_ = {w2_, w2_}, W3_ = {w3_, w3_}; \
    uint4 R_; \
    R_.x = comb2(P[0].x, P[1].x, P[2].x, P[3].x, W0_, W1_, W2_, W3_); \
    R_.y = comb2(P[0].y, P[1].y, P[2].y, P[3].y, W0_, W1_, W2_, W3_); \
    R_.z = comb2(P[0].z, P[1].z, P[2].z, P[3].z, W0_, W1_, W2_, W3_); \
    R_.w = comb2(P[0].w, P[1].w, P[2].w, P[3].w, W0_, W1_, W2_, W3_); \
    *(uint4*)&col_sh[wv][pt_ * 72 + gck * 8] = R_; }

    // prefetch tap-0 offset/mask
    float offy = omp[0];
    float offx = omp[HWSZ];
    float mk   = omp[18 * HWSZ];

    for (int k = 0; k < 9; ++k) {
        // owner: bilinear corner setup for this lane's point
        float ys = (float)(h + (k / 3) - 1) + offy;
        float xs = (float)(w + (k % 3) - 1) + offx;
        float fy0 = floorf(ys), fx0 = floorf(xs);
        float wy1 = ys - fy0, wx1 = xs - fx0;
        float wy0 = 1.f - wy1, wx0 = 1.f - wx1;
        int y0 = (int)fy0, x0 = (int)fx0;
        int y1 = y0 + 1, x1 = x0 + 1;
        bool vy0 = (y0 >= 0) && (y0 < HH), vy1 = (y1 >= 0) && (y1 < HH);
        bool vx0 = (x0 >= 0) && (x0 < WW), vx1 = (x1 >= 0) && (x1 < WW);
        int y0c = min(max(y0, 0), HH - 1), y1c = min(max(y1, 0), HH - 1);
        int x0c = min(max(x0, 0), WW - 1), x1c = min(max(x1, 0), WW - 1);
        unsigned a0 = (unsigned)((y0c * WW + x0c) << 7);
        unsigned a1 = (unsigned)((y0c * WW + x1c) << 7);
        unsigned a2 = (unsigned)((y1c * WW + x0c) << 7);
        unsigned a3 = (unsigned)((y1c * WW + x1c) << 7);
        float wb0 = (vy0 && vx0) ? mk * wy0 * wx0 : 0.f;
        float wb1 = (vy0 && vx1) ? mk * wy0 * wx1 : 0.f;
        float wb2 = (vy1 && vx0) ? mk * wy1 * wx0 : 0.f;
        float wb3 = (vy1 && vx1) ? mk * wy1 * wx1 : 0.f;
        // prefetch next tap's offset/mask
        int kn = (k < 8) ? k + 1 : 8;
        offy = omp[(2 * kn) * HWSZ];
        offx = omp[(2 * kn + 1) * HWSZ];
        mk   = omp[(18 + kn) * HWSZ];

        // prefetch this tap's weight fragments (L1/L2-resident)
        const unsigned short* wk = wdT + k * 4096;
        bf16x8 af[2][4];
#pragma unroll
        for (int ks = 0; ks < 2; ++ks)
#pragma unroll
            for (int mt = 0; mt < 4; ++mt)
                af[ks][mt] = *(const bf16x8*)(wk + (mt * 16 + l15) * 64 + ks * 32 + q * 8);

        // gather + combine, distance-2 pipeline over 8 groups
        uint4 pb[3][4];
        LOADG(pb[0], 0);
        LOADG(pb[1], 1);
#pragma unroll
        for (int g = 0; g < 8; ++g) {
            if (g + 2 < 8) LOADG(pb[(g + 2) % 3], g + 2);
            COMBG(pb[g % 3], g);
        }
        __builtin_amdgcn_wave_barrier();

        // MFMA over this tap's K=64
#pragma unroll
        for (int ks = 0; ks < 2; ++ks) {
            bf16x8 bfr[4];
#pragma unroll
            for (int nt = 0; nt < 4; ++nt)
                bfr[nt] = *(const bf16x8*)&col_sh[wv][(nt * 16 + l15) * 72 + ks * 32 + q * 8];
#pragma unroll
            for (int mt = 0; mt < 4; ++mt)
#pragma unroll
                for (int nt = 0; nt < 4; ++nt)
                    acc[mt][nt] = __builtin_amdgcn_mfma_f32_16x16x32_bf16(
                        af[ks][mt], bfr[nt], acc[mt][nt], 0, 0, 0);
        }
        __builtin_amdgcn_wave_barrier();   // col_sh reuse next tap
    }
#undef LOADG
#undef COMBG

    // epilogue: bias add, store, per-(b,co) sum/sumsq partials
    const int p0 = pblk + wv * 64;
    float* outb = out + (size_t)b * COUT * HWSZ;
#pragma unroll
    for (int mt = 0; mt < 4; ++mt)
#pragma unroll
        for (int r = 0; r < 4; ++r) {
            int co = mt * 16 + q * 4 + r;
            float bias = bd[co];
            float s = 0.f, qq = 0.f;
#pragma unroll
            for (int nt = 0; nt < 4; ++nt) {
                float v = acc[mt][nt][r] + bias;
                outb[(size_t)co * HWSZ + p0 + nt * 16 + l15] = v;
                s += v; qq += v * v;
            }
#pragma unroll
            for (int m = 1; m < 16; m <<= 1) {
                s += __shfl_xor(s, m);
                qq += __shfl_xor(qq, m);
            }
            if (l15 == 0) { redS[wv][co] = s; redQ[wv][co] = qq; }
        }
    __syncthreads();
    if (t < 64) {
        float S = redS[0][t] + redS[1][t] + redS[2][t] + redS[3][t];
        float Q = redQ[0][t] + redQ[1][t] + redQ[2][t] + redQ[3][t];
        atomicAdd(&sums[b * 64 + t].x, S);
        atomicAdd(&sums[b * 64 + t].y, Q);
    }
}

// ---------------------------------------------------------------------------
// k_norm: in-place normalize + ReLU, float4, XCD-swizzled (b = id & 7).
// ---------------------------------------------------------------------------
__global__ __launch_bounds__(256) void k_norm(float* __restrict__ out,
                                              const float2* __restrict__ sums)
{
    const int id = blockIdx.x;
    const int b = id & 7;
    const int rest = id >> 3;            // 0..1023
    const int co = rest >> 4;            // 0..63
    const int off = rest & 15;           // 0..15
    const int bco = b * 64 + co;
    const int i = (bco << 12) + off * 256 + threadIdx.x;   // float4 index
    float2 sq = sums[bco];
    float mu  = sq.x * (1.f / (float)HWSZ);
    float var = sq.y * (1.f / (float)HWSZ) - mu * mu;
    float rstd = rsqrtf(var + 1e-5f);
    float4* o4 = (float4*)out;
    float4 v = o4[i];
    v.x = fmaxf((v.x - mu) * rstd, 0.f);
    v.y = fmaxf((v.y - mu) * rstd, 0.f);
    v.z = fmaxf((v.z - mu) * rstd, 0.f);
    v.w = fmaxf((v.w - mu) * rstd, 0.f);
    o4[i] = v;
}

extern "C" void kernel_launch(void* const* d_in, const int* in_sizes, int n_in,
                              void* d_out, int out_size, void* d_ws, size_t ws_size,
                              hipStream_t stream) {
    const float* x   = (const float*)d_in[0];
    const float* wof = (const float*)d_in[1];
    const float* bof = (const float*)d_in[2];
    const float* wd  = (const float*)d_in[3];
    const float* bd  = (const float*)d_in[4];
    float* out = (float*)d_out;

    char* ws = (char*)d_ws;
    unsigned short* xT   = (unsigned short*)ws;                  // 16,777,216 B
    float*          om   = (float*)(ws + 16777216);              // 14,155,776 B
    unsigned short* wdT  = (unsigned short*)(ws + 30932992);     //     73,728 B
    unsigned short* wofT = (unsigned short*)(ws + 31006720);     //     36,864 B
    float2*         sums = (float2*)(ws + 31043584);             //      4,096 B

    k_tr    <<<576, 256, 0, stream>>>(x, wd, wof, xT, wdT, wofT, (float4*)sums);
    k_off   <<<512, 256, 0, stream>>>(xT, wofT, bof, om);
    k_dcn   <<<512, 256, 0, stream>>>(xT, om, wdT, bd, out, sums);
    k_norm  <<<8192, 256, 0, stream>>>(out, (const float2*)sums);
}

// Round 10
// 181.685 us; speedup vs baseline: 1.3197x; 1.3197x over previous
//
#include <hip/hip_runtime.h>
#include <hip/hip_bf16.h>

#define BB   8
#define CIN  64
#define COUT 64
#define HH   128
#define WW   128
#define HWSZ (HH * WW)

typedef short bf16x8 __attribute__((ext_vector_type(8)));
typedef float f32x4  __attribute__((ext_vector_type(4)));
typedef float f32x2  __attribute__((ext_vector_type(2)));

__device__ __forceinline__ unsigned f2bf_u(float f) {
    unsigned u = __float_as_uint(f);
    return (u + 0x7fffu + ((u >> 16) & 1u)) >> 16;
}

// packed bilinear combine of one 2-channel pair across 4 corners (v_pk_fma_f32)
__device__ __forceinline__ unsigned comb2(unsigned a, unsigned b, unsigned c, unsigned d,
                                          f32x2 W0, f32x2 W1, f32x2 W2, f32x2 W3) {
    f32x2 A = {__uint_as_float(a << 16), __uint_as_float(a & 0xffff0000u)};
    f32x2 B = {__uint_as_float(b << 16), __uint_as_float(b & 0xffff0000u)};
    f32x2 C = {__uint_as_float(c << 16), __uint_as_float(c & 0xffff0000u)};
    f32x2 D = {__uint_as_float(d << 16), __uint_as_float(d & 0xffff0000u)};
    f32x2 r = A * W0;
    r += B * W1;
    r += C * W2;
    r += D * W3;
    __hip_bfloat162 h = __float22bfloat162_rn(make_float2(r.x, r.y));
    return *(const unsigned*)&h;
}

// ---------------------------------------------------------------------------
// k_tr: x NCHW fp32 -> xT NHWC bf16, XCD-swizzled (b = id & 7).
//       Blocks 512..575: weight repack; block 512 also zeroes sums.
// ---------------------------------------------------------------------------
__global__ __launch_bounds__(256) void k_tr(const float* __restrict__ x,
                                            const float* __restrict__ wd,
                                            const float* __restrict__ wof,
                                            unsigned short* __restrict__ xT,
                                            unsigned short* __restrict__ wdT,
                                            unsigned short* __restrict__ wofT,
                                            float4* __restrict__ sums4)
{
    const int t = threadIdx.x;
    const int id = blockIdx.x;
    if (id >= 512) {
        if (id == 512) sums4[t] = make_float4(0.f, 0.f, 0.f, 0.f);  // 4096 B
        int base = (id - 512) * 256 + t;
#pragma unroll
        for (int j = 0; j < 4; ++j) {
            int idx = base + j * 16384;
            if (idx < 36864) {
                int k = idx >> 12, rem = idx & 4095, co = rem >> 6, c = rem & 63;
                wdT[idx] = (unsigned short)f2bf_u(wd[(co * 64 + c) * 9 + k]);
            } else if (idx < 55296) {
                int jj = idx - 36864;
                int k = jj >> 11, rem = jj & 2047, o = rem >> 6, c = rem & 63;
                wofT[jj] = (o < 27) ? (unsigned short)f2bf_u(wof[(o * 64 + c) * 9 + k]) : 0;
            }
        }
        return;
    }
    __shared__ unsigned short tile[256 * 66];
    const int b = id & 7;                 // XCD = linear_id % 8 = b
    const int p0 = (id >> 3) * 256;
#pragma unroll
    for (int i = 0; i < 16; ++i) {
        int c = i * 4 + (t >> 6);
        int pl = (t & 63) * 4;
        float4 v = *(const float4*)(x + (((size_t)b * 64 + c) << 14) + p0 + pl);
        tile[(pl + 0) * 66 + c] = (unsigned short)f2bf_u(v.x);
        tile[(pl + 1) * 66 + c] = (unsigned short)f2bf_u(v.y);
        tile[(pl + 2) * 66 + c] = (unsigned short)f2bf_u(v.z);
        tile[(pl + 3) * 66 + c] = (unsigned short)f2bf_u(v.w);
    }
    __syncthreads();
#pragma unroll
    for (int i = 0; i < 8; ++i) {
        int idd = i * 256 + t;
        int pt = idd >> 3, ck = idd & 7;
        const unsigned* srcp = (const unsigned*)&tile[pt * 66 + ck * 8];
        uint4 r;
        r.x = srcp[0]; r.y = srcp[1]; r.z = srcp[2]; r.w = srcp[3];
        *(uint4*)(xT + ((size_t)b << 20) + (size_t)(p0 + pt) * 64 + ck * 8) = r;
    }
}

// ---------------------------------------------------------------------------
// k_off: offset conv, XCD-swizzled. 4-row x 130-col zero-padded halo tile;
//        inner loop = pure ds_read + MFMA.
// ---------------------------------------------------------------------------
__global__ __launch_bounds__(256, 2) void k_off(
    const unsigned short* __restrict__ xT, const unsigned short* __restrict__ wofT,
    const float* __restrict__ bof, float* __restrict__ om)
{
    __shared__ unsigned short tile[8 * 521 * 8];   // 66,688 B
    const int t = threadIdx.x;
    const int lane = t & 63, wv = t >> 6;
    const int q = lane >> 4, l15 = lane & 15;
    const int b = blockIdx.x & 7;                  // XCD = b
    const int xblk = blockIdx.x >> 3;
    const int h0 = xblk * 2;
    const int r0 = h0 - 1;
    const unsigned short* xb = xT + ((size_t)b << 20);

#pragma unroll
    for (int i = 0; i < 17; ++i) {
        int id = i * 256 + t;
        if (id < 4160) {
            int m = id & 7, lin = id >> 3;
            int row = lin / 130, col = lin % 130;
            int gy = r0 + row, gx = col - 1;
            uint4 v = {0u, 0u, 0u, 0u};
            if (((unsigned)gy < (unsigned)HH) && ((unsigned)gx < (unsigned)WW))
                v = *(const uint4*)(xb + ((size_t)(gy * WW + gx) << 6) + m * 8);
            *(uint4*)&tile[(m * 521 + lin) * 8] = v;
        }
    }
    __syncthreads();

    const int hrow = h0 + (wv >> 1);
    const int c0 = (wv & 1) * 64;

    f32x4 acc[2][4];
#pragma unroll
    for (int mt = 0; mt < 2; ++mt)
#pragma unroll
        for (int nt = 0; nt < 4; ++nt) acc[mt][nt] = (f32x4){0.f, 0.f, 0.f, 0.f};

#pragma unroll
    for (int k = 0; k < 9; ++k) {
        const int ky = k / 3 - 1, kx = k % 3 - 1;
        const int trow = (hrow - h0) + ky + 1;
        const unsigned short* wk = wofT + k * 2048;
#pragma unroll
        for (int ks = 0; ks < 2; ++ks) {
            bf16x8 af[2], bfr[4];
#pragma unroll
            for (int mt = 0; mt < 2; ++mt)
                af[mt] = *(const bf16x8*)(wk + (mt * 16 + l15) * 64 + ks * 32 + q * 8);
#pragma unroll
            for (int nt = 0; nt < 4; ++nt) {
                int tc = c0 + nt * 16 + l15 + kx + 1;
                bfr[nt] = *(const bf16x8*)&tile[((ks * 4 + q) * 521 + trow * 130 + tc) * 8];
            }
#pragma unroll
            for (int mt = 0; mt < 2; ++mt)
#pragma unroll
                for (int nt = 0; nt < 4; ++nt)
                    acc[mt][nt] = __builtin_amdgcn_mfma_f32_16x16x32_bf16(
                        af[mt], bfr[nt], acc[mt][nt], 0, 0, 0);
        }
    }

    const int p0 = xblk * 256 + wv * 64;
    float* omb = om + (size_t)b * 27 * HWSZ;
#pragma unroll
    for (int mt = 0; mt < 2; ++mt)
#pragma unroll
        for (int r = 0; r < 4; ++r) {
            int o = mt * 16 + q * 4 + r;
            if (o < 27) {
                float bias = bof[o];
#pragma unroll
                for (int nt = 0; nt < 4; ++nt) {
                    int pp = p0 + nt * 16 + l15;
                    float v = acc[mt][nt][r] + bias;
                    if (o >= 18) v = 1.f / (1.f + __expf(-v));
                    omb[(size_t)o * HWSZ + pp] = v;
                }
            }
        }
}

// ---------------------------------------------------------------------------
// k_dcn: 32 pts/wave (1024 blocks = 4 blocks/CU, 16 waves/CU) + XCD swizzle
//        (each XCD gathers only its own L2-resident 2MB batch slice).
//        LDS publish for addrs/weights (round-8 proven), col stride 80
//        (conflict-free), distance-2 gather pipeline, packed combine, MFMA,
//        fused stats. acc[4][2] = 32 VGPRs -> no spill at (256,4).
// ---------------------------------------------------------------------------
__global__ __launch_bounds__(256, 4) void k_dcn(
    const unsigned short* __restrict__ xT, const float* __restrict__ om,
    const unsigned short* __restrict__ wdT, const float* __restrict__ bd,
    float* __restrict__ out, float2* __restrict__ sums)
{
    __shared__ unsigned short col_sh[4][32 * 80];   // 20480 B
    __shared__ unsigned       adr_sh[4][4][32];     //  2048 B
    __shared__ float4         w_sh[4][32];          //  2048 B
    __shared__ float          redS[4][64];          //  1024 B
    __shared__ float          redQ[4][64];          //  1024 B

    const int t = threadIdx.x;
    const int lane = t & 63, wv = t >> 6;
    const int q = lane >> 4, l15 = lane & 15;
    const int b = blockIdx.x & 7;                   // XCD = b
    const int wp0 = (blockIdx.x >> 3) * 128 + wv * 32;  // wave's first point
    const int myp = wp0 + (lane & 31);              // owner point (lanes 0..31)
    const int h = myp >> 7, w = myp & 127;
    const char* xbB = (const char*)(xT + ((size_t)b << 20));
    const float* omp = om + (size_t)b * 27 * HWSZ + myp;
    const int gck = lane & 7;

    f32x4 acc[4][2];
#pragma unroll
    for (int mt = 0; mt < 4; ++mt)
#pragma unroll
        for (int nt = 0; nt < 2; ++nt) acc[mt][nt] = (f32x4){0.f, 0.f, 0.f, 0.f};

#define LOADG(P, g) { \
    int pt_ = (g) * 8 + (lane >> 3); \
    unsigned o0_ = adr_sh[wv][0][pt_]; \
    unsigned o1_ = adr_sh[wv][1][pt_]; \
    unsigned o2_ = adr_sh[wv][2][pt_]; \
    unsigned o3_ = adr_sh[wv][3][pt_]; \
    int bo_ = gck * 16; \
    P[0] = *(const uint4*)(xbB + o0_ + bo_); \
    P[1] = *(const uint4*)(xbB + o1_ + bo_); \
    P[2] = *(const uint4*)(xbB + o2_ + bo_); \
    P[3] = *(const uint4*)(xbB + o3_ + bo_); }

#define COMBG(P, g) { \
    int pt_ = (g) * 8 + (lane >> 3); \
    float4 w4_ = w_sh[wv][pt_]; \
    f32x2 W0_ = {w4_.x, w4_.x}, W1_ = {w4_.y, w4_.y}; \
    f32x2 W2_ = {w4_.z, w4_.z}, W3_ = {w4_.w, w4_.w}; \
    uint4 R_; \
    R_.x = comb2(P[0].x, P[1].x, P[2].x, P[3].x, W0_, W1_, W2_, W3_); \
    R_.y = comb2(P[0].y, P[1].y, P[2].y, P[3].y, W0_, W1_, W2_, W3_); \
    R_.z = comb2(P[0].z, P[1].z, P[2].z, P[3].z, W0_, W1_, W2_, W3_); \
    R_.w = comb2(P[0].w, P[1].w, P[2].w, P[3].w, W0_, W1_, W2_, W3_); \
    *(uint4*)&col_sh[wv][pt_ * 80 + gck * 8] = R_; }

    // prefetch tap-0 offset/mask (owner lanes only)
    float offy = 0.f, offx = 0.f, mk = 0.f;
    if (lane < 32) {
        offy = omp[0];
        offx = omp[HWSZ];
        mk   = omp[18 * HWSZ];
    }

    for (int k = 0; k < 9; ++k) {
        if (lane < 32) {
            float ys = (float)(h + (k / 3) - 1) + offy;
            float xs = (float)(w + (k % 3) - 1) + offx;
            float fy0 = floorf(ys), fx0 = floorf(xs);
            float wy1 = ys - fy0, wx1 = xs - fx0;
            float wy0 = 1.f - wy1, wx0 = 1.f - wx1;
            int y0 = (int)fy0, x0 = (int)fx0;
            int y1 = y0 + 1, x1 = x0 + 1;
            bool vy0 = (y0 >= 0) && (y0 < HH), vy1 = (y1 >= 0) && (y1 < HH);
            bool vx0 = (x0 >= 0) && (x0 < WW), vx1 = (x1 >= 0) && (x1 < WW);
            int y0c = min(max(y0, 0), HH - 1), y1c = min(max(y1, 0), HH - 1);
            int x0c = min(max(x0, 0), WW - 1), x1c = min(max(x1, 0), WW - 1);
            int pl = lane & 31;
            adr_sh[wv][0][pl] = (unsigned)((y0c * WW + x0c) << 7);
            adr_sh[wv][1][pl] = (unsigned)((y0c * WW + x1c) << 7);
            adr_sh[wv][2][pl] = (unsigned)((y1c * WW + x0c) << 7);
            adr_sh[wv][3][pl] = (unsigned)((y1c * WW + x1c) << 7);
            w_sh[wv][pl] = make_float4((vy0 && vx0) ? mk * wy0 * wx0 : 0.f,
                                       (vy0 && vx1) ? mk * wy0 * wx1 : 0.f,
                                       (vy1 && vx0) ? mk * wy1 * wx0 : 0.f,
                                       (vy1 && vx1) ? mk * wy1 * wx1 : 0.f);
            int kn = (k < 8) ? k + 1 : 8;
            offy = omp[(2 * kn) * HWSZ];
            offx = omp[(2 * kn + 1) * HWSZ];
            mk   = omp[(18 + kn) * HWSZ];
        }
        __builtin_amdgcn_wave_barrier();

        // prefetch this tap's weight fragments (L1/L2-resident)
        const unsigned short* wk = wdT + k * 4096;
        bf16x8 af[2][4];
#pragma unroll
        for (int ks = 0; ks < 2; ++ks)
#pragma unroll
            for (int mt = 0; mt < 4; ++mt)
                af[ks][mt] = *(const bf16x8*)(wk + (mt * 16 + l15) * 64 + ks * 32 + q * 8);

        // gather + combine, distance-2 pipeline over 4 groups (8 pts each)
        uint4 pb[3][4];
        LOADG(pb[0], 0);
        LOADG(pb[1], 1);
#pragma unroll
        for (int g = 0; g < 4; ++g) {
            if (g + 2 < 4) LOADG(pb[(g + 2) % 3], g + 2);
            COMBG(pb[g % 3], g);
        }
        __builtin_amdgcn_wave_barrier();

        // MFMA over this tap's K=64, C tile = 64co x 32pt
#pragma unroll
        for (int ks = 0; ks < 2; ++ks) {
            bf16x8 bfr[2];
#pragma unroll
            for (int nt = 0; nt < 2; ++nt)
                bfr[nt] = *(const bf16x8*)&col_sh[wv][(nt * 16 + l15) * 80 + ks * 32 + q * 8];
#pragma unroll
            for (int mt = 0; mt < 4; ++mt)
#pragma unroll
                for (int nt = 0; nt < 2; ++nt)
                    acc[mt][nt] = __builtin_amdgcn_mfma_f32_16x16x32_bf16(
                        af[ks][mt], bfr[nt], acc[mt][nt], 0, 0, 0);
        }
        __builtin_amdgcn_wave_barrier();   // col_sh reuse next tap
    }
#undef LOADG
#undef COMBG

    // epilogue: bias add, store, per-(b,co) sum/sumsq partials
    float* outb = out + (size_t)b * COUT * HWSZ;
#pragma unroll
    for (int mt = 0; mt < 4; ++mt)
#pragma unroll
        for (int r = 0; r < 4; ++r) {
            int co = mt * 16 + q * 4 + r;
            float bias = bd[co];
            float s = 0.f, qq = 0.f;
#pragma unroll
            for (int nt = 0; nt < 2; ++nt) {
                float v = acc[mt][nt][r] + bias;
                outb[(size_t)co * HWSZ + wp0 + nt * 16 + l15] = v;
                s += v; qq += v * v;
            }
#pragma unroll
            for (int m = 1; m < 16; m <<= 1) {
                s += __shfl_xor(s, m);
                qq += __shfl_xor(qq, m);
            }
            if (l15 == 0) { redS[wv][co] = s; redQ[wv][co] = qq; }
        }
    __syncthreads();
    if (t < 64) {
        float S = redS[0][t] + redS[1][t] + redS[2][t] + redS[3][t];
        float Q = redQ[0][t] + redQ[1][t] + redQ[2][t] + redQ[3][t];
        atomicAdd(&sums[b * 64 + t].x, S);
        atomicAdd(&sums[b * 64 + t].y, Q);
    }
}

// ---------------------------------------------------------------------------
// k_norm: in-place normalize + ReLU, float4, XCD-swizzled (b = id & 7).
// ---------------------------------------------------------------------------
__global__ __launch_bounds__(256) void k_norm(float* __restrict__ out,
                                              const float2* __restrict__ sums)
{
    const int id = blockIdx.x;
    const int b = id & 7;
    const int rest = id >> 3;            // 0..1023
    const int co = rest >> 4;            // 0..63
    const int off = rest & 15;           // 0..15
    const int bco = b * 64 + co;
    const int i = (bco << 12) + off * 256 + threadIdx.x;   // float4 index
    float2 sq = sums[bco];
    float mu  = sq.x * (1.f / (float)HWSZ);
    float var = sq.y * (1.f / (float)HWSZ) - mu * mu;
    float rstd = rsqrtf(var + 1e-5f);
    float4* o4 = (float4*)out;
    float4 v = o4[i];
    v.x = fmaxf((v.x - mu) * rstd, 0.f);
    v.y = fmaxf((v.y - mu) * rstd, 0.f);
    v.z = fmaxf((v.z - mu) * rstd, 0.f);
    v.w = fmaxf((v.w - mu) * rstd, 0.f);
    o4[i] = v;
}

extern "C" void kernel_launch(void* const* d_in, const int* in_sizes, int n_in,
                              void* d_out, int out_size, void* d_ws, size_t ws_size,
                              hipStream_t stream) {
    const float* x   = (const float*)d_in[0];
    const float* wof = (const float*)d_in[1];
    const float* bof = (const float*)d_in[2];
    const float* wd  = (const float*)d_in[3];
    const float* bd  = (const float*)d_in[4];
    float* out = (float*)d_out;

    char* ws = (char*)d_ws;
    unsigned short* xT   = (unsigned short*)ws;                  // 16,777,216 B
    float*          om   = (float*)(ws + 16777216);              // 14,155,776 B
    unsigned short* wdT  = (unsigned short*)(ws + 30932992);     //     73,728 B
    unsigned short* wofT = (unsigned short*)(ws + 31006720);     //     36,864 B
    float2*         sums = (float2*)(ws + 31043584);             //      4,096 B

    k_tr    <<<576, 256, 0, stream>>>(x, wd, wof, xT, wdT, wofT, (float4*)sums);
    k_off   <<<512, 256, 0, stream>>>(xT, wofT, bof, om);
    k_dcn   <<<1024, 256, 0, stream>>>(xT, om, wdT, bd, out, sums);
    k_norm  <<<8192, 256, 0, stream>>>(out, (const float2*)sums);
}

// Round 11
// 171.266 us; speedup vs baseline: 1.4000x; 1.0608x over previous
//
#include <hip/hip_runtime.h>
#include <hip/hip_fp16.h>

#define BB   8
#define CIN  64
#define COUT 64
#define HH   128
#define WW   128
#define HWSZ (HH * WW)

typedef _Float16 f16x8 __attribute__((ext_vector_type(8)));
typedef _Float16 h2v   __attribute__((ext_vector_type(2)));
typedef float    f32x4 __attribute__((ext_vector_type(4)));

__device__ __forceinline__ unsigned short f2h_u(float f) {
    __half h = __float2half(f);
    return __half_as_ushort(h);
}
// duplicated packed half2 (both lanes = f16(f))
__device__ __forceinline__ unsigned duph(float f) {
    unsigned u = (unsigned)f2h_u(f);
    return u | (u << 16);
}

// packed bilinear combine of one 2-channel f16 pair across 4 corners:
// pure v_pk_mul/v_pk_fma_f16, no unpacking.
__device__ __forceinline__ unsigned comb2h(unsigned a, unsigned b, unsigned c, unsigned d,
                                           h2v W0, h2v W1, h2v W2, h2v W3) {
    h2v A = *(h2v*)&a, B = *(h2v*)&b, C = *(h2v*)&c, D = *(h2v*)&d;
    h2v r = A * W0;
    r += B * W1;
    r += C * W2;
    r += D * W3;
    return *(unsigned*)&r;
}

// ---------------------------------------------------------------------------
// k_tr: x NCHW fp32 -> xT NHWC f16, XCD-swizzled (b = id & 7).
//       Blocks 512..575: weight repack (f16); block 512 also zeroes sums.
// ---------------------------------------------------------------------------
__global__ __launch_bounds__(256) void k_tr(const float* __restrict__ x,
                                            const float* __restrict__ wd,
                                            const float* __restrict__ wof,
                                            unsigned short* __restrict__ xT,
                                            unsigned short* __restrict__ wdT,
                                            unsigned short* __restrict__ wofT,
                                            float4* __restrict__ sums4)
{
    const int t = threadIdx.x;
    const int id = blockIdx.x;
    if (id >= 512) {
        if (id == 512) sums4[t] = make_float4(0.f, 0.f, 0.f, 0.f);  // 4096 B
        int base = (id - 512) * 256 + t;
#pragma unroll
        for (int j = 0; j < 4; ++j) {
            int idx = base + j * 16384;
            if (idx < 36864) {
                int k = idx >> 12, rem = idx & 4095, co = rem >> 6, c = rem & 63;
                wdT[idx] = f2h_u(wd[(co * 64 + c) * 9 + k]);
            } else if (idx < 55296) {
                int jj = idx - 36864;
                int k = jj >> 11, rem = jj & 2047, o = rem >> 6, c = rem & 63;
                wofT[jj] = (o < 27) ? f2h_u(wof[(o * 64 + c) * 9 + k]) : 0;
            }
        }
        return;
    }
    __shared__ unsigned short tile[256 * 66];
    const int b = id & 7;                 // XCD = linear_id % 8 = b
    const int p0 = (id >> 3) * 256;
#pragma unroll
    for (int i = 0; i < 16; ++i) {
        int c = i * 4 + (t >> 6);
        int pl = (t & 63) * 4;
        float4 v = *(const float4*)(x + (((size_t)b * 64 + c) << 14) + p0 + pl);
        tile[(pl + 0) * 66 + c] = f2h_u(v.x);
        tile[(pl + 1) * 66 + c] = f2h_u(v.y);
        tile[(pl + 2) * 66 + c] = f2h_u(v.z);
        tile[(pl + 3) * 66 + c] = f2h_u(v.w);
    }
    __syncthreads();
#pragma unroll
    for (int i = 0; i < 8; ++i) {
        int idd = i * 256 + t;
        int pt = idd >> 3, ck = idd & 7;
        const unsigned* srcp = (const unsigned*)&tile[pt * 66 + ck * 8];
        uint4 r;
        r.x = srcp[0]; r.y = srcp[1]; r.z = srcp[2]; r.w = srcp[3];
        *(uint4*)(xT + ((size_t)b << 20) + (size_t)(p0 + pt) * 64 + ck * 8) = r;
    }
}

// ---------------------------------------------------------------------------
// k_off: offset conv (f16 MFMA), XCD-swizzled. 4-row x 130-col zero-padded
//        halo tile; inner loop = pure ds_read + MFMA.
// ---------------------------------------------------------------------------
__global__ __launch_bounds__(256, 2) void k_off(
    const unsigned short* __restrict__ xT, const unsigned short* __restrict__ wofT,
    const float* __restrict__ bof, float* __restrict__ om)
{
    __shared__ unsigned short tile[8 * 521 * 8];   // 66,688 B
    const int t = threadIdx.x;
    const int lane = t & 63, wv = t >> 6;
    const int q = lane >> 4, l15 = lane & 15;
    const int b = blockIdx.x & 7;                  // XCD = b
    const int xblk = blockIdx.x >> 3;
    const int h0 = xblk * 2;
    const int r0 = h0 - 1;
    const unsigned short* xb = xT + ((size_t)b << 20);

#pragma unroll
    for (int i = 0; i < 17; ++i) {
        int id = i * 256 + t;
        if (id < 4160) {
            int m = id & 7, lin = id >> 3;
            int row = lin / 130, col = lin % 130;
            int gy = r0 + row, gx = col - 1;
            uint4 v = {0u, 0u, 0u, 0u};
            if (((unsigned)gy < (unsigned)HH) && ((unsigned)gx < (unsigned)WW))
                v = *(const uint4*)(xb + ((size_t)(gy * WW + gx) << 6) + m * 8);
            *(uint4*)&tile[(m * 521 + lin) * 8] = v;
        }
    }
    __syncthreads();

    const int hrow = h0 + (wv >> 1);
    const int c0 = (wv & 1) * 64;

    f32x4 acc[2][4];
#pragma unroll
    for (int mt = 0; mt < 2; ++mt)
#pragma unroll
        for (int nt = 0; nt < 4; ++nt) acc[mt][nt] = (f32x4){0.f, 0.f, 0.f, 0.f};

#pragma unroll
    for (int k = 0; k < 9; ++k) {
        const int ky = k / 3 - 1, kx = k % 3 - 1;
        const int trow = (hrow - h0) + ky + 1;
        const unsigned short* wk = wofT + k * 2048;
#pragma unroll
        for (int ks = 0; ks < 2; ++ks) {
            f16x8 af[2], bfr[4];
#pragma unroll
            for (int mt = 0; mt < 2; ++mt)
                af[mt] = *(const f16x8*)(wk + (mt * 16 + l15) * 64 + ks * 32 + q * 8);
#pragma unroll
            for (int nt = 0; nt < 4; ++nt) {
                int tc = c0 + nt * 16 + l15 + kx + 1;
                bfr[nt] = *(const f16x8*)&tile[((ks * 4 + q) * 521 + trow * 130 + tc) * 8];
            }
#pragma unroll
            for (int mt = 0; mt < 2; ++mt)
#pragma unroll
                for (int nt = 0; nt < 4; ++nt)
                    acc[mt][nt] = __builtin_amdgcn_mfma_f32_16x16x32_f16(
                        af[mt], bfr[nt], acc[mt][nt], 0, 0, 0);
        }
    }

    const int p0 = xblk * 256 + wv * 64;
    float* omb = om + (size_t)b * 27 * HWSZ;
#pragma unroll
    for (int mt = 0; mt < 2; ++mt)
#pragma unroll
        for (int r = 0; r < 4; ++r) {
            int o = mt * 16 + q * 4 + r;
            if (o < 27) {
                float bias = bof[o];
#pragma unroll
                for (int nt = 0; nt < 4; ++nt) {
                    int pp = p0 + nt * 16 + l15;
                    float v = acc[mt][nt][r] + bias;
                    if (o >= 18) v = 1.f / (1.f + __expf(-v));
                    omb[(size_t)o * HWSZ + pp] = v;
                }
            }
        }
}

// ---------------------------------------------------------------------------
// k_dcn: round-8 geometry (64 pts/wave, 512 blocks, 2 blocks/CU, stride 80,
//        LDS publish) with f16 data: combine = pure v_pk_fma_f16 (no unpack),
//        MFMA f16. XCD-swizzled. Fused stats.
// ---------------------------------------------------------------------------
__global__ __launch_bounds__(256, 2) void k_dcn(
    const unsigned short* __restrict__ xT, const float* __restrict__ om,
    const unsigned short* __restrict__ wdT, const float* __restrict__ bd,
    float* __restrict__ out, float2* __restrict__ sums)
{
    __shared__ unsigned short col_sh[4][64 * 80];   // 40960 B
    __shared__ unsigned       adr_sh[4][4][64];     //  4096 B
    __shared__ uint4          w_sh[4][64];          //  4096 B (packed half2 x4)
    __shared__ float          redS[4][64];          //  1024 B
    __shared__ float          redQ[4][64];          //  1024 B

    const int t = threadIdx.x;
    const int lane = t & 63, wv = t >> 6;
    const int q = lane >> 4, l15 = lane & 15;
    const int b = blockIdx.x & 7;                   // XCD = b
    const int pblk = (blockIdx.x >> 3) * 256;
    const int p = pblk + t;
    const int h = p >> 7, w = p & 127;
    const char* xbB = (const char*)(xT + ((size_t)b << 20));
    const float* omp = om + (size_t)b * 27 * HWSZ + p;
    const int gck = lane & 7;

    f32x4 acc[4][4];
#pragma unroll
    for (int mt = 0; mt < 4; ++mt)
#pragma unroll
        for (int nt = 0; nt < 4; ++nt) acc[mt][nt] = (f32x4){0.f, 0.f, 0.f, 0.f};

#define LOADG(P, g) { \
    int pt_ = (g) * 8 + (lane >> 3); \
    unsigned o0_ = adr_sh[wv][0][pt_]; \
    unsigned o1_ = adr_sh[wv][1][pt_]; \
    unsigned o2_ = adr_sh[wv][2][pt_]; \
    unsigned o3_ = adr_sh[wv][3][pt_]; \
    int bo_ = gck * 16; \
    P[0] = *(const uint4*)(xbB + o0_ + bo_); \
    P[1] = *(const uint4*)(xbB + o1_ + bo_); \
    P[2] = *(const uint4*)(xbB + o2_ + bo_); \
    P[3] = *(const uint4*)(xbB + o3_ + bo_); }

#define COMBG(P, g) { \
    int pt_ = (g) * 8 + (lane >> 3); \
    uint4 pw_ = w_sh[wv][pt_]; \
    h2v W0_ = *(h2v*)&pw_.x, W1_ = *(h2v*)&pw_.y; \
    h2v W2_ = *(h2v*)&pw_.z, W3_ = *(h2v*)&pw_.w; \
    uint4 R_; \
    R_.x = comb2h(P[0].x, P[1].x, P[2].x, P[3].x, W0_, W1_, W2_, W3_); \
    R_.y = comb2h(P[0].y, P[1].y, P[2].y, P[3].y, W0_, W1_, W2_, W3_); \
    R_.z = comb2h(P[0].z, P[1].z, P[2].z, P[3].z, W0_, W1_, W2_, W3_); \
    R_.w = comb2h(P[0].w, P[1].w, P[2].w, P[3].w, W0_, W1_, W2_, W3_); \
    *(uint4*)&col_sh[wv][pt_ * 80 + gck * 8] = R_; }

    // prefetch tap-0 offset/mask
    float offy = omp[0];
    float offx = omp[HWSZ];
    float mk   = omp[18 * HWSZ];

    for (int k = 0; k < 9; ++k) {
        // owner: bilinear corner setup for this lane's point
        float ys = (float)(h + (k / 3) - 1) + offy;
        float xs = (float)(w + (k % 3) - 1) + offx;
        float fy0 = floorf(ys), fx0 = floorf(xs);
        float wy1 = ys - fy0, wx1 = xs - fx0;
        float wy0 = 1.f - wy1, wx0 = 1.f - wx1;
        int y0 = (int)fy0, x0 = (int)fx0;
        int y1 = y0 + 1, x1 = x0 + 1;
        bool vy0 = (y0 >= 0) && (y0 < HH), vy1 = (y1 >= 0) && (y1 < HH);
        bool vx0 = (x0 >= 0) && (x0 < WW), vx1 = (x1 >= 0) && (x1 < WW);
        int y0c = min(max(y0, 0), HH - 1), y1c = min(max(y1, 0), HH - 1);
        int x0c = min(max(x0, 0), WW - 1), x1c = min(max(x1, 0), WW - 1);
        adr_sh[wv][0][lane] = (unsigned)((y0c * WW + x0c) << 7);
        adr_sh[wv][1][lane] = (unsigned)((y0c * WW + x1c) << 7);
        adr_sh[wv][2][lane] = (unsigned)((y1c * WW + x0c) << 7);
        adr_sh[wv][3][lane] = (unsigned)((y1c * WW + x1c) << 7);
        w_sh[wv][lane] = make_uint4(
            duph((vy0 && vx0) ? mk * wy0 * wx0 : 0.f),
            duph((vy0 && vx1) ? mk * wy0 * wx1 : 0.f),
            duph((vy1 && vx0) ? mk * wy1 * wx0 : 0.f),
            duph((vy1 && vx1) ? mk * wy1 * wx1 : 0.f));
        int kn = (k < 8) ? k + 1 : 8;
        offy = omp[(2 * kn) * HWSZ];
        offx = omp[(2 * kn + 1) * HWSZ];
        mk   = omp[(18 + kn) * HWSZ];
        __builtin_amdgcn_wave_barrier();

        // prefetch this tap's weight fragments (L1/L2-resident)
        const unsigned short* wk = wdT + k * 4096;
        f16x8 af[2][4];
#pragma unroll
        for (int ks = 0; ks < 2; ++ks)
#pragma unroll
            for (int mt = 0; mt < 4; ++mt)
                af[ks][mt] = *(const f16x8*)(wk + (mt * 16 + l15) * 64 + ks * 32 + q * 8);

        // gather + combine, distance-2 pipeline over 8 groups
        uint4 pb[3][4];
        LOADG(pb[0], 0);
        LOADG(pb[1], 1);
#pragma unroll
        for (int g = 0; g < 8; ++g) {
            if (g + 2 < 8) LOADG(pb[(g + 2) % 3], g + 2);
            COMBG(pb[g % 3], g);
        }
        __builtin_amdgcn_wave_barrier();

        // MFMA over this tap's K=64
#pragma unroll
        for (int ks = 0; ks < 2; ++ks) {
            f16x8 bfr[4];
#pragma unroll
            for (int nt = 0; nt < 4; ++nt)
                bfr[nt] = *(const f16x8*)&col_sh[wv][(nt * 16 + l15) * 80 + ks * 32 + q * 8];
#pragma unroll
            for (int mt = 0; mt < 4; ++mt)
#pragma unroll
                for (int nt = 0; nt < 4; ++nt)
                    acc[mt][nt] = __builtin_amdgcn_mfma_f32_16x16x32_f16(
                        af[ks][mt], bfr[nt], acc[mt][nt], 0, 0, 0);
        }
    }
#undef LOADG
#undef COMBG

    // epilogue: bias add, store, per-(b,co) sum/sumsq partials
    const int p0 = pblk + wv * 64;
    float* outb = out + (size_t)b * COUT * HWSZ;
#pragma unroll
    for (int mt = 0; mt < 4; ++mt)
#pragma unroll
        for (int r = 0; r < 4; ++r) {
            int co = mt * 16 + q * 4 + r;
            float bias = bd[co];
            float s = 0.f, qq = 0.f;
#pragma unroll
            for (int nt = 0; nt < 4; ++nt) {
                float v = acc[mt][nt][r] + bias;
                outb[(size_t)co * HWSZ + p0 + nt * 16 + l15] = v;
                s += v; qq += v * v;
            }
#pragma unroll
            for (int m = 1; m < 16; m <<= 1) {
                s += __shfl_xor(s, m);
                qq += __shfl_xor(qq, m);
            }
            if (l15 == 0) { redS[wv][co] = s; redQ[wv][co] = qq; }
        }
    __syncthreads();
    if (t < 64) {
        float S = redS[0][t] + redS[1][t] + redS[2][t] + redS[3][t];
        float Q = redQ[0][t] + redQ[1][t] + redQ[2][t] + redQ[3][t];
        atomicAdd(&sums[b * 64 + t].x, S);
        atomicAdd(&sums[b * 64 + t].y, Q);
    }
}

// ---------------------------------------------------------------------------
// k_norm: in-place normalize + ReLU, float4, XCD-swizzled (b = id & 7).
// ---------------------------------------------------------------------------
__global__ __launch_bounds__(256) void k_norm(float* __restrict__ out,
                                              const float2* __restrict__ sums)
{
    const int id = blockIdx.x;
    const int b = id & 7;
    const int rest = id >> 3;            // 0..1023
    const int co = rest >> 4;            // 0..63
    const int off = rest & 15;           // 0..15
    const int bco = b * 64 + co;
    const int i = (bco << 12) + off * 256 + threadIdx.x;   // float4 index
    float2 sq = sums[bco];
    float mu  = sq.x * (1.f / (float)HWSZ);
    float var = sq.y * (1.f / (float)HWSZ) - mu * mu;
    float rstd = rsqrtf(var + 1e-5f);
    float4* o4 = (float4*)out;
    float4 v = o4[i];
    v.x = fmaxf((v.x - mu) * rstd, 0.f);
    v.y = fmaxf((v.y - mu) * rstd, 0.f);
    v.z = fmaxf((v.z - mu) * rstd, 0.f);
    v.w = fmaxf((v.w - mu) * rstd, 0.f);
    o4[i] = v;
}

extern "C" void kernel_launch(void* const* d_in, const int* in_sizes, int n_in,
                              void* d_out, int out_size, void* d_ws, size_t ws_size,
                              hipStream_t stream) {
    const float* x   = (const float*)d_in[0];
    const float* wof = (const float*)d_in[1];
    const float* bof = (const float*)d_in[2];
    const float* wd  = (const float*)d_in[3];
    const float* bd  = (const float*)d_in[4];
    float* out = (float*)d_out;

    char* ws = (char*)d_ws;
    unsigned short* xT   = (unsigned short*)ws;                  // 16,777,216 B
    float*          om   = (float*)(ws + 16777216);              // 14,155,776 B
    unsigned short* wdT  = (unsigned short*)(ws + 30932992);     //     73,728 B
    unsigned short* wofT = (unsigned short*)(ws + 31006720);     //     36,864 B
    float2*         sums = (float2*)(ws + 31043584);             //      4,096 B

    k_tr    <<<576, 256, 0, stream>>>(x, wd, wof, xT, wdT, wofT, (float4*)sums);
    k_off   <<<512, 256, 0, stream>>>(xT, wofT, bof, om);
    k_dcn   <<<512, 256, 0, stream>>>(xT, om, wdT, bd, out, sums);
    k_norm  <<<8192, 256, 0, stream>>>(out, (const float2*)sums);
}